// Round 1
// 230.308 us; speedup vs baseline: 1.0700x; 1.0700x over previous
//
#include <hip/hip_runtime.h>
#include <hip/hip_fp16.h>
#include <stdint.h>

#define O_FEAT 4096
#define I_FEAT 4096
#define M_DIM  2048
#define K_DIM  4096

typedef __attribute__((ext_vector_type(8))) short short8;   // 8 x bf16 (4 VGPRs)
typedef __attribute__((ext_vector_type(2))) short short2v;  // 2 x bf16 (1 VGPR)
typedef __attribute__((ext_vector_type(4))) float floatx4;  // MFMA accumulator

#define AS1 __attribute__((address_space(1)))
#define AS3 __attribute__((address_space(3)))

__device__ __forceinline__ uint16_t f32_to_bf16(float f) {
    uint32_t u = __builtin_bit_cast(uint32_t, f);
    u = (u + 0x7FFFu + ((u >> 16) & 1u)) >> 16;   // round-to-nearest-even
    return (uint16_t)u;
}
__device__ __forceinline__ float bf16_to_f32(uint16_t h) {
    uint32_t u = ((uint32_t)h) << 16;
    return __builtin_bit_cast(float, u);
}

// async global->LDS, 16B per lane; LDS dest = wave-uniform base + lane*16
__device__ __forceinline__ void load_lds16(const uint16_t* gptr, uint16_t* ldsptr) {
    __builtin_amdgcn_global_load_lds((const AS1 uint32_t*)gptr,
                                     (AS3 uint32_t*)ldsptr, 16, 0, 0);
}

// ---------------------------------------------------------------------------
// Kernel 1: dequant int4 -> bf16 W.  (unchanged from 245.9 µs baseline)
// ---------------------------------------------------------------------------
__global__ __launch_bounds__(256) void dequant_kernel(
        const void*  __restrict__ packed,
        const float* __restrict__ scales,
        uint16_t*    __restrict__ W) {
    const int lane = threadIdx.x & 63;
    uint32_t probe = ((const uint32_t*)packed)[lane];
    const bool int32mode = (__ballot(probe >= 256u) == 0ull);

    int idx = blockIdx.x * 256 + threadIdx.x;       // 2,097,152 threads
    float s = scales[idx >> 9];                     // 512 byte-quads per row

    uint32_t bytes4;
    if (int32mode) {
        uint4 w = ((const uint4*)packed)[idx];      // 4 int32, each 0..255
        bytes4 = (w.x & 0xFFu) | ((w.y & 0xFFu) << 8) |
                 ((w.z & 0xFFu) << 16) | ((w.w & 0xFFu) << 24);
    } else {
        bytes4 = ((const uint32_t*)packed)[idx];
    }

    uint16_t o[8];
#pragma unroll
    for (int b = 0; b < 4; ++b) {
        int byte = (bytes4 >> (8 * b)) & 0xFF;
        o[2 * b]     = f32_to_bf16((float)((byte & 0xF) - 8) * s);  // low -> even
        o[2 * b + 1] = f32_to_bf16((float)((byte >> 4) - 8) * s);   // high -> odd
    }
    uint4 v;
    v.x = (uint32_t)o[0] | ((uint32_t)o[1] << 16);
    v.y = (uint32_t)o[2] | ((uint32_t)o[3] << 16);
    v.z = (uint32_t)o[4] | ((uint32_t)o[5] << 16);
    v.w = (uint32_t)o[6] | ((uint32_t)o[7] << 16);
    ((uint4*)W)[idx] = v;
}

// ---------------------------------------------------------------------------
// Kernel 2 (fused): scatter COO residual into W + x fp32 -> bf16 Xb.
// (unchanged from 245.9 µs baseline)
// ---------------------------------------------------------------------------
#define SCATTER_BLOCKS 3328
__global__ __launch_bounds__(256) void scatter_xconv_kernel(
        const void*  __restrict__ vals,
        const int*   __restrict__ rows,
        const int*   __restrict__ cols,
        const float* __restrict__ alpha,
        const float* __restrict__ x,
        uint16_t*    __restrict__ W,
        uint16_t*    __restrict__ Xb,
        int nnz) {
    if (blockIdx.x < SCATTER_BLOCKS) {
        const int lane = threadIdx.x & 63;
        float p = fabsf(((const float*)vals)[lane]);
        int cnt = __popcll(__ballot(p > 1e-4f && p < 1.0f));
        const bool f32mode = (cnt >= 32);

        int i = blockIdx.x * 256 + threadIdx.x;
        if (i >= nnz) return;
        float v = f32mode ? ((const float*)vals)[i]
                          : __half2float(((const __half*)vals)[i]);
        v *= alpha[0];
        int r = rows[i], c = cols[i];
        size_t elem = (size_t)r * I_FEAT + c;

#if __has_builtin(__builtin_amdgcn_global_atomic_fadd_v2bf16)
        const bool hi = (elem & 1);
        short b = (short)f32_to_bf16(v);
        short2v val;
        val[0] = hi ? (short)0 : b;
        val[1] = hi ? b : (short)0;
        __builtin_amdgcn_global_atomic_fadd_v2bf16(
            (AS1 short2v*)(W + (elem & ~(size_t)1)), val);
#else
        uint32_t* word = (uint32_t*)W + (elem >> 1);
        bool hi = (c & 1);
        uint32_t old = *word, assumed;
        do {
            assumed = old;
            uint16_t cur = hi ? (uint16_t)(assumed >> 16) : (uint16_t)(assumed & 0xFFFF);
            uint16_t nw  = f32_to_bf16(bf16_to_f32(cur) + v);
            uint32_t neww = hi ? ((assumed & 0x0000FFFFu) | ((uint32_t)nw << 16))
                               : ((assumed & 0xFFFF0000u) | (uint32_t)nw);
            old = atomicCAS(word, assumed, neww);
        } while (old != assumed);
#endif
    } else {
        int idx = (blockIdx.x - SCATTER_BLOCKS) * 256 + threadIdx.x;  // 1,048,576
        float4 v0 = ((const float4*)x)[2 * idx];
        float4 v1 = ((const float4*)x)[2 * idx + 1];
        uint4 o;
        o.x = (uint32_t)f32_to_bf16(v0.x) | ((uint32_t)f32_to_bf16(v0.y) << 16);
        o.y = (uint32_t)f32_to_bf16(v0.z) | ((uint32_t)f32_to_bf16(v0.w) << 16);
        o.z = (uint32_t)f32_to_bf16(v1.x) | ((uint32_t)f32_to_bf16(v1.y) << 16);
        o.w = (uint32_t)f32_to_bf16(v1.z) | ((uint32_t)f32_to_bf16(v1.w) << 16);
        ((uint4*)Xb)[idx] = o;
    }
}

// ---------------------------------------------------------------------------
// Kernel 3: C[M,N] = A[M,K] * B[N,K]^T  (bf16 in, fp32 out).
// R9: phase-interleaved schedule (T3+T4) + LDS XOR-swizzle (T2) + setprio (T5)
// + XCD block swizzle (T1).  BM=128 BN=256 BK=64, 8 waves (2Mx4N), per-wave
// 64x64 (4x4 frags of 16x16x32).  3 LDS buffers (144 KiB) -> prefetch depth 2
// tiles, steady-state s_waitcnt vmcnt(6) (never 0 in main loop).
// Staging: global_load_lds w=16 with PRE-SWIZZLED global source
// (slot (r,q) sources k-quad q^(r&7)); reads XOR (fr&7)<<3 into k-offset.
// Fragment lane mapping + C/D epilogue identical to passing baseline.
// ---------------------------------------------------------------------------
#define BM 128
#define BN 256
#define BK 64
#define NT (K_DIM / BK)                 // 64
#define A_ELEMS (BM * BK)               // 8192
#define B_ELEMS (BN * BK)               // 16384
#define TILE_ELEMS (A_ELEMS + B_ELEMS)  // 24576 elems = 48 KiB

#define MFMA16(d, a, b) d = __builtin_amdgcn_mfma_f32_16x16x32_bf16(a, b, d, 0, 0, 0)

__global__ __launch_bounds__(512, 2) void gemm_bt_kernel(
        const uint16_t* __restrict__ A,   // [2048][4096] bf16
        const uint16_t* __restrict__ B,   // [4096][4096] bf16 (row-major [N][K])
        float* __restrict__ C) {          // [2048][4096] fp32
    __shared__ uint16_t lds[3 * TILE_ELEMS];   // 144 KiB, 3 rotating buffers

    const int tid  = threadIdx.x;
    const int wave = tid >> 6;
    const int lane = tid & 63;
    const int wm   = wave >> 2;          // 0..1  (64 rows each)
    const int wn   = wave & 3;           // 0..3  (64 cols each)

    // XCD-aware bijective block swizzle: 256 blocks, 8 XCDs (256 % 8 == 0)
    const int wgid = blockIdx.y * 16 + blockIdx.x;
    const int swz  = (wgid & 7) * 32 + (wgid >> 3);
    const int bm0  = (swz >> 4) * BM;
    const int bn0  = (swz & 15) * BN;

    // ---- staging addresses: thread -> 16B slot, source pre-swizzled ----
    // slot s = i*512 + tid covers LDS bytes s*16; row r = s>>3, quad q = lane&7.
    // slot (r,q) sources global k-quad (q ^ (r&7));  r&7 == lane>>3.
    const int srow = (wave << 3) + (lane >> 3);              // 0..63
    const int xcol = ((lane & 7) ^ (lane >> 3)) << 3;        // swizzled k-elem
    const uint16_t* gA0 = A + (size_t)(bm0 + srow) * K_DIM + xcol;
    const uint16_t* gA1 = gA0 + (size_t)64 * K_DIM;
    const uint16_t* gB0 = B + (size_t)(bn0 + srow) * K_DIM + xcol;
    const uint16_t* gB1 = gB0 + (size_t)64  * K_DIM;
    const uint16_t* gB2 = gB0 + (size_t)128 * K_DIM;
    const uint16_t* gB3 = gB0 + (size_t)192 * K_DIM;
    const int ldsA0 = wave * 512;
    const int ldsA1 = 4096 + wave * 512;
    const int ldsB0 = A_ELEMS + wave * 512;
    const int ldsB1 = A_ELEMS + 4096 + wave * 512;
    const int ldsB2 = A_ELEMS + 8192 + wave * 512;
    const int ldsB3 = A_ELEMS + 12288 + wave * 512;

    // ---- LDS read addressing (swizzle matches staging; conflict-free) ----
    const int fr  = lane & 15;                  // fragment row
    const int ko  = (lane >> 4) << 3;           // fragment k offset in 32-slice
    const int sk0 = (ko)      ^ ((fr & 7) << 3);
    const int sk1 = (32 + ko) ^ ((fr & 7) << 3);
    const int raA = (wm * 64 + fr) * BK;                 // + i*1024
    const int raB = A_ELEMS + (wn * 64 + fr) * BK;       // + j*1024

    floatx4 acc[4][4];
#pragma unroll
    for (int i = 0; i < 4; ++i)
#pragma unroll
        for (int j = 0; j < 4; ++j) acc[i][j] = {0.f, 0.f, 0.f, 0.f};

    // ---- prologue: stage tile0 -> buf0, tile1 -> buf1 (6 loads each) ----
    load_lds16(gA0, &lds[ldsA0]);
    load_lds16(gA1, &lds[ldsA1]);
    load_lds16(gB0, &lds[ldsB0]);
    load_lds16(gB1, &lds[ldsB1]);
    load_lds16(gB2, &lds[ldsB2]);
    load_lds16(gB3, &lds[ldsB3]);
    load_lds16(gA0 + BK, &lds[TILE_ELEMS + ldsA0]);
    load_lds16(gA1 + BK, &lds[TILE_ELEMS + ldsA1]);
    load_lds16(gB0 + BK, &lds[TILE_ELEMS + ldsB0]);
    load_lds16(gB1 + BK, &lds[TILE_ELEMS + ldsB1]);
    load_lds16(gB2 + BK, &lds[TILE_ELEMS + ldsB2]);
    load_lds16(gB3 + BK, &lds[TILE_ELEMS + ldsB3]);
    asm volatile("s_waitcnt vmcnt(6)" ::: "memory");   // tile0 landed
    __builtin_amdgcn_s_barrier();

    int cbo = 0;                 // compute buffer (tile t)   : buffer t%3
    int sbo = 2 * TILE_ELEMS;    // stage buffer (tile t+2)   : buffer (t+2)%3

    for (int t = 0; t < NT; ++t) {
        const bool pf   = (t + 2 < NT);
        const int  kofs = (t + 2) * BK;

        // ---------------- phase 0: read A0,A1 + B0,B1; stage A(t+2) ----------
        short8 a00 = *(const short8*)&lds[cbo + raA + sk0];
        short8 a01 = *(const short8*)&lds[cbo + raA + sk1];
        short8 a10 = *(const short8*)&lds[cbo + raA + 1024 + sk0];
        short8 a11 = *(const short8*)&lds[cbo + raA + 1024 + sk1];
        short8 b00 = *(const short8*)&lds[cbo + raB + sk0];
        short8 b01 = *(const short8*)&lds[cbo + raB + sk1];
        short8 b10 = *(const short8*)&lds[cbo + raB + 1024 + sk0];
        short8 b11 = *(const short8*)&lds[cbo + raB + 1024 + sk1];
        if (pf) {
            load_lds16(gA0 + kofs, &lds[sbo + ldsA0]);
            load_lds16(gA1 + kofs, &lds[sbo + ldsA1]);
        }
        __builtin_amdgcn_s_barrier();
        asm volatile("s_waitcnt lgkmcnt(0)");
        __builtin_amdgcn_s_setprio(1);
        MFMA16(acc[0][0], a00, b00); MFMA16(acc[0][0], a01, b01);
        MFMA16(acc[0][1], a00, b10); MFMA16(acc[0][1], a01, b11);
        MFMA16(acc[1][0], a10, b00); MFMA16(acc[1][0], a11, b01);
        MFMA16(acc[1][1], a10, b10); MFMA16(acc[1][1], a11, b11);
        __builtin_amdgcn_s_setprio(0);
        __builtin_amdgcn_s_barrier();

        // ---------------- phase 1: read B2,B3; stage B01(t+2) ----------------
        short8 b20 = *(const short8*)&lds[cbo + raB + 2048 + sk0];
        short8 b21 = *(const short8*)&lds[cbo + raB + 2048 + sk1];
        short8 b30 = *(const short8*)&lds[cbo + raB + 3072 + sk0];
        short8 b31 = *(const short8*)&lds[cbo + raB + 3072 + sk1];
        if (pf) {
            load_lds16(gB0 + kofs, &lds[sbo + ldsB0]);
            load_lds16(gB1 + kofs, &lds[sbo + ldsB1]);
        }
        __builtin_amdgcn_s_barrier();
        asm volatile("s_waitcnt lgkmcnt(0)");
        __builtin_amdgcn_s_setprio(1);
        MFMA16(acc[0][2], a00, b20); MFMA16(acc[0][2], a01, b21);
        MFMA16(acc[0][3], a00, b30); MFMA16(acc[0][3], a01, b31);
        MFMA16(acc[1][2], a10, b20); MFMA16(acc[1][2], a11, b21);
        MFMA16(acc[1][3], a10, b30); MFMA16(acc[1][3], a11, b31);
        __builtin_amdgcn_s_setprio(0);
        __builtin_amdgcn_s_barrier();

        // ---------------- phase 2: read A2,A3; stage B23(t+2) ----------------
        short8 a20 = *(const short8*)&lds[cbo + raA + 2048 + sk0];
        short8 a21 = *(const short8*)&lds[cbo + raA + 2048 + sk1];
        short8 a30 = *(const short8*)&lds[cbo + raA + 3072 + sk0];
        short8 a31 = *(const short8*)&lds[cbo + raA + 3072 + sk1];
        if (pf) {
            load_lds16(gB2 + kofs, &lds[sbo + ldsB2]);
            load_lds16(gB3 + kofs, &lds[sbo + ldsB3]);
        }
        __builtin_amdgcn_s_barrier();
        asm volatile("s_waitcnt lgkmcnt(0)");
        __builtin_amdgcn_s_setprio(1);
        MFMA16(acc[2][2], a20, b20); MFMA16(acc[2][2], a21, b21);
        MFMA16(acc[2][3], a20, b30); MFMA16(acc[2][3], a21, b31);
        MFMA16(acc[3][2], a30, b20); MFMA16(acc[3][2], a31, b21);
        MFMA16(acc[3][3], a30, b30); MFMA16(acc[3][3], a31, b31);
        __builtin_amdgcn_s_setprio(0);
        __builtin_amdgcn_s_barrier();

        // ---------------- phase 3: reuse regs; counted vmcnt; tile barrier ---
        __builtin_amdgcn_s_setprio(1);
        MFMA16(acc[2][0], a20, b00); MFMA16(acc[2][0], a21, b01);
        MFMA16(acc[2][1], a20, b10); MFMA16(acc[2][1], a21, b11);
        MFMA16(acc[3][0], a30, b00); MFMA16(acc[3][0], a31, b01);
        MFMA16(acc[3][1], a30, b10); MFMA16(acc[3][1], a31, b11);
        __builtin_amdgcn_s_setprio(0);
        if (t + 2 < NT) {
            // outstanding: tile t+1 (6, oldest) + tile t+2 (6) -> drain t+1
            asm volatile("s_waitcnt vmcnt(6)" ::: "memory");
        } else if (t + 1 < NT) {
            // t == NT-2: only tile NT-1's 6 loads outstanding -> drain all
            asm volatile("s_waitcnt vmcnt(0)" ::: "memory");
        }
        if (t + 1 < NT) __builtin_amdgcn_s_barrier();

        cbo += TILE_ELEMS; if (cbo == 3 * TILE_ELEMS) cbo = 0;
        sbo += TILE_ELEMS; if (sbo == 3 * TILE_ELEMS) sbo = 0;
    }

    // epilogue: C/D layout col=lane&15, row=(lane>>4)*4+reg   [m89/m91]
    const int cn  = lane & 15;
    const int rb4 = (lane >> 4) * 4;
#pragma unroll
    for (int i = 0; i < 4; ++i)
#pragma unroll
        for (int j = 0; j < 4; ++j)
#pragma unroll
            for (int r = 0; r < 4; ++r) {
                const int row = bm0 + wm * 64 + i * 16 + rb4 + r;
                const int col = bn0 + wn * 64 + j * 16 + cn;
                C[(size_t)row * O_FEAT + col] = acc[i][j][r];
            }
}

// ---------------------------------------------------------------------------
extern "C" void kernel_launch(void* const* d_in, const int* in_sizes, int n_in,
                              void* d_out, int out_size, void* d_ws, size_t ws_size,
                              hipStream_t stream) {
    const float* x      = (const float*)d_in[0];
    const void*  packed = d_in[1];
    const float* scales = (const float*)d_in[2];
    const void*  vals   = d_in[3];
    const int*   rows   = (const int*)d_in[4];
    const int*   cols   = (const int*)d_in[5];
    const float* alpha  = (const float*)d_in[6];
    float*       out    = (float*)d_out;
    const int nnz = in_sizes[3];

    uint16_t* W  = (uint16_t*)d_ws;                                        // 32 MB
    uint16_t* Xb = (uint16_t*)((char*)d_ws + (size_t)O_FEAT * I_FEAT * 2); // 16 MB

    // 1) dequant int4 -> bf16 W
    dequant_kernel<<<8192, 256, 0, stream>>>(packed, scales, W);
    // 2) fused: scatter residual into W (blocks < 3328) + x -> bf16 (rest)
    scatter_xconv_kernel<<<SCATTER_BLOCKS + 4096, 256, 0, stream>>>(
        vals, rows, cols, alpha, x, W, Xb, nnz);
    // 3) GEMM: out = Xb (2048x4096) * W^T (4096x4096)
    gemm_bt_kernel<<<dim3(O_FEAT / BN, M_DIM / BM), 512, 0, stream>>>(Xb, W, out);
}